// Round 1
// baseline (2217.436 us; speedup 1.0000x reference)
//
#include <hip/hip_runtime.h>
#include <stdint.h>

// ---- problem constants ----
// B=1, S=2048, HID=4096, NH=32, D=128, HP=16
#define LAMBDA_INIT_F 0.35550906759096927f
#define ONE_MINUS_LI_F 0.6444909324090307f
#define QSCALE_F 0.08838834764831845f   // 1/sqrt(128)

typedef __attribute__((ext_vector_type(8))) short bf16x8;
typedef __attribute__((ext_vector_type(4))) float f32x4;

__device__ __forceinline__ unsigned short f2bf(float x) {
    union { float f; uint32_t u; } v; v.f = x;
    uint32_t r = v.u + 0x7fffu + ((v.u >> 16) & 1u);
    return (unsigned short)(r >> 16);
}
__device__ __forceinline__ float bf2f(unsigned short h) {
    union { uint32_t u; float f; } v; v.u = ((uint32_t)h) << 16;
    return v.f;
}
__device__ __forceinline__ f32x4 mfma16(bf16x8 a, bf16x8 b, f32x4 c) {
    return __builtin_amdgcn_mfma_f32_16x16x32_bf16(a, b, c, 0, 0, 0);
}
// split fp32 -> (hi,lo) bf16; hi+lo ~= x to ~2^-16 rel
__device__ __forceinline__ void split_store8(float4 a, float4 b,
                                             unsigned short* dh, unsigned short* dl) {
    union { unsigned short u[8]; bf16x8 v; } H, L;
    float f[8] = {a.x, a.y, a.z, a.w, b.x, b.y, b.z, b.w};
    #pragma unroll
    for (int e = 0; e < 8; ++e) {
        unsigned short hh = f2bf(f[e]);
        H.u[e] = hh;
        L.u[e] = f2bf(f[e] - bf2f(hh));
    }
    *(bf16x8*)dh = H.v;
    *(bf16x8*)dl = L.v;
}

// ============================================================================
// Split-bf16 GEMM: C[M,N] = A[M,K] * B[N,K]^T + bias, fp32 in, 3-product MFMA.
// 128x128 tile, BK=64, 256 threads (4 waves, each 64x64).
// MODE 0: QKV epilogue (scatter q*scale / k / v-transposed as bf16 hi/lo)
// MODE 1: plain fp32 output
// ============================================================================
template<int MODE>
__global__ __launch_bounds__(256, 2) void gemm_split_kernel(
    const float* __restrict__ A, const float* __restrict__ Bm,
    const float* __restrict__ bias, int M, int N, int K,
    unsigned short* __restrict__ qh, unsigned short* __restrict__ ql,
    unsigned short* __restrict__ kh, unsigned short* __restrict__ kl,
    unsigned short* __restrict__ vh, unsigned short* __restrict__ vl,
    float* __restrict__ Cout)
{
    // padded rows: 72 ushorts = 144B (multiple of 16B -> aligned b128, ~2-way banks)
    __shared__ unsigned short sAh[128 * 72], sAl[128 * 72];
    __shared__ unsigned short sBh[128 * 72], sBl[128 * 72];

    const int nwg = gridDim.x;
    const int bid = blockIdx.x;
    const int wg  = (bid & 7) * (nwg >> 3) + (bid >> 3);   // XCD swizzle (nwg % 8 == 0)
    const int mt  = M >> 7;
    const int bm  = wg % mt, bn = wg / mt;
    const int rowA = bm << 7, rowB = bn << 7;

    const int t  = threadIdx.x;
    const int g  = t & 7, mr = t >> 3;          // staging: 8 k-groups x 32 rows
    const int ln = t & 63, w = t >> 6;
    const int wm = (w >> 1) << 6, wn = (w & 1) << 6;
    const int lr = ln & 15, lg = ln >> 4;

    const f32x4 zero4 = {0.f, 0.f, 0.f, 0.f};
    f32x4 acc[4][4];
    #pragma unroll
    for (int a = 0; a < 4; ++a)
        #pragma unroll
        for (int b = 0; b < 4; ++b) acc[a][b] = zero4;

    for (int k0 = 0; k0 < K; k0 += 64) {
        // ---- stage: fp32 global -> regs -> split bf16 hi/lo -> LDS ----
        float4 st[16];
        #pragma unroll
        for (int i = 0; i < 4; ++i) {
            const float* sa = A  + (size_t)(rowA + mr + 32 * i) * K + k0 + g * 8;
            const float* sb = Bm + (size_t)(rowB + mr + 32 * i) * K + k0 + g * 8;
            st[2 * i]     = *(const float4*)sa;
            st[2 * i + 1] = *(const float4*)(sa + 4);
            st[8 + 2 * i]     = *(const float4*)sb;
            st[8 + 2 * i + 1] = *(const float4*)(sb + 4);
        }
        #pragma unroll
        for (int i = 0; i < 4; ++i) {
            const int off = (mr + 32 * i) * 72 + g * 8;
            split_store8(st[2 * i],     st[2 * i + 1],     &sAh[off], &sAl[off]);
            split_store8(st[8 + 2 * i], st[8 + 2 * i + 1], &sBh[off], &sBl[off]);
        }
        __syncthreads();

        // ---- compute: 2 k-chunks of 32, 3-product split MFMA ----
        #pragma unroll
        for (int kk = 0; kk < 2; ++kk) {
            bf16x8 ah[4], al_[4], bh[4], bl_[4];
            const int ko = kk * 32 + lg * 8;
            #pragma unroll
            for (int mf = 0; mf < 4; ++mf) {
                const int off = (wm + mf * 16 + lr) * 72 + ko;
                ah[mf]  = *(const bf16x8*)&sAh[off];
                al_[mf] = *(const bf16x8*)&sAl[off];
            }
            #pragma unroll
            for (int nf = 0; nf < 4; ++nf) {
                const int off = (wn + nf * 16 + lr) * 72 + ko;
                bh[nf]  = *(const bf16x8*)&sBh[off];
                bl_[nf] = *(const bf16x8*)&sBl[off];
            }
            #pragma unroll
            for (int mf = 0; mf < 4; ++mf)
                #pragma unroll
                for (int nf = 0; nf < 4; ++nf) {
                    acc[mf][nf] = mfma16(ah[mf],  bh[nf],  acc[mf][nf]);
                    acc[mf][nf] = mfma16(ah[mf],  bl_[nf], acc[mf][nf]);
                    acc[mf][nf] = mfma16(al_[mf], bh[nf],  acc[mf][nf]);
                }
        }
        __syncthreads();
    }

    // ---- epilogue (C/D layout: col = lane&15, row = (lane>>4)*4 + i) ----
    #pragma unroll
    for (int nf = 0; nf < 4; ++nf) {
        const int n  = (bn << 7) + wn + nf * 16 + lr;
        const float bv = bias[n];
        #pragma unroll
        for (int mf = 0; mf < 4; ++mf) {
            #pragma unroll
            for (int i = 0; i < 4; ++i) {
                const int srow = (bm << 7) + wm + mf * 16 + lg * 4 + i;
                const float val = acc[mf][nf][i] + bv;
                if (MODE == 0) {
                    if (n < 4096) {           // q: pre-scale by 1/sqrt(D)
                        const int hh = n >> 8, e2 = (n >> 7) & 1, d = n & 127;
                        const float qv = val * QSCALE_F;
                        const unsigned short hi = f2bf(qv);
                        const unsigned short lo = f2bf(qv - bf2f(hi));
                        const size_t o = ((size_t)((hh * 2 + e2) * 2048 + srow)) * 128 + d;
                        qh[o] = hi; ql[o] = lo;
                    } else if (n < 8192) {    // k
                        const int n2 = n - 4096;
                        const int hh = n2 >> 8, e2 = (n2 >> 7) & 1, d = n2 & 127;
                        const unsigned short hi = f2bf(val);
                        const unsigned short lo = f2bf(val - bf2f(hi));
                        const size_t o = ((size_t)((hh * 2 + e2) * 2048 + srow)) * 128 + d;
                        kh[o] = hi; kl[o] = lo;
                    } else {                  // v: store transposed vT[h][c][s]
                        const int n2 = n - 8192;
                        const int hh = n2 >> 8, cc = n2 & 255;
                        const unsigned short hi = f2bf(val);
                        const unsigned short lo = f2bf(val - bf2f(hi));
                        const size_t o = ((size_t)(hh * 256 + cc)) * 2048 + srow;
                        vh[o] = hi; vl[o] = lo;
                    }
                } else {
                    Cout[(size_t)srow * N + n] = val;
                }
            }
        }
    }
}

// ============================================================================
// Flash attention, dual-e per block (shared V staging).
// 512 threads = 8 waves; waves 0-3: e=0, waves 4-7: e=1; same 64 q-rows.
// K tile 32 keys, split hi/lo; online fp32 softmax; P split hi/lo via LDS.
// ============================================================================
__global__ __launch_bounds__(512, 2) void attn_kernel(
    const unsigned short* __restrict__ qh, const unsigned short* __restrict__ ql,
    const unsigned short* __restrict__ kh, const unsigned short* __restrict__ kl,
    const unsigned short* __restrict__ vh, const unsigned short* __restrict__ vl,
    float* __restrict__ att1, float* __restrict__ att2)
{
    __shared__ unsigned short sK[2][2][32 * 136];   // [e][hi/lo][key*136 + d], 136 = 128+8 pad
    __shared__ unsigned short sV[2][256 * 40];      // [hi/lo][c*40 + key],     40  = 32+8  pad
    __shared__ unsigned short sP[8][2][16 * 40];    // [wave][hi/lo][q*40 + key]

    const int qt = blockIdx.x;          // 0..31 (64 q-rows each)
    const int h  = blockIdx.y;          // 0..15
    const int t  = threadIdx.x;
    const int w  = t >> 6, ln = t & 63;
    const int e  = w >> 2, wq = w & 3;
    const int lr = ln & 15, lg = ln >> 4;
    const int qr0 = qt * 64 + wq * 16;

    // Q fragments (A-layout: row = lane&15, k = (lane>>4)*8 + j), q pre-scaled
    bf16x8 qfh[4], qfl[4];
    {
        const size_t qoff = ((size_t)((h * 2 + e) * 2048 + qr0 + lr)) * 128 + lg * 8;
        #pragma unroll
        for (int kk = 0; kk < 4; ++kk) {
            qfh[kk] = *(const bf16x8*)(qh + qoff + kk * 32);
            qfl[kk] = *(const bf16x8*)(ql + qoff + kk * 32);
        }
    }

    const f32x4 zero4 = {0.f, 0.f, 0.f, 0.f};
    f32x4 o[16];
    #pragma unroll
    for (int nf = 0; nf < 16; ++nf) o[nf] = zero4;
    float mrun[4] = {-3.0e38f, -3.0e38f, -3.0e38f, -3.0e38f};
    float lrun[4] = {0.f, 0.f, 0.f, 0.f};

    const int ktiles = qt * 2 + 2;      // causal: keys up to (qt+1)*64
    for (int kt = 0; kt < ktiles; ++kt) {
        // ---- stage K(e=0,1, hi/lo) + V(hi/lo); 4096 16B-groups, 8/thread ----
        bf16x8 stg[8];
        unsigned short* dstp[8];
        #pragma unroll
        for (int i = 0; i < 8; ++i) {
            const int gid = i * 512 + t;
            if (gid < 2048) {           // K groups: [buf(4)][key(32)][dg(16)]
                const int buf = gid >> 9, r = gid & 511;
                const int e2 = buf >> 1, hl = buf & 1;
                const int key = r >> 4, dg = r & 15;
                const unsigned short* base = hl ? kl : kh;
                stg[i]  = *(const bf16x8*)(base +
                          ((size_t)((h * 2 + e2) * 2048 + kt * 32 + key)) * 128 + dg * 8);
                dstp[i] = &sK[e2][hl][key * 136 + dg * 8];
            } else {                    // V groups: [hl(2)][c(256)][kg(4)]
                const int r2 = gid - 2048;
                const int hl = r2 >> 10, r = r2 & 1023;
                const int c = r >> 2, kg = r & 3;
                const unsigned short* base = hl ? vl : vh;
                stg[i]  = *(const bf16x8*)(base +
                          ((size_t)(h * 256 + c)) * 2048 + kt * 32 + kg * 8);
                dstp[i] = &sV[hl][c * 40 + kg * 8];
            }
        }
        #pragma unroll
        for (int i = 0; i < 8; ++i) *(bf16x8*)dstp[i] = stg[i];
        __syncthreads();

        // ---- scores: S = Q * K^T (split, 3-product), fp32 accum ----
        f32x4 s[2];
        s[0] = zero4; s[1] = zero4;
        #pragma unroll
        for (int kk = 0; kk < 4; ++kk) {
            const int ko = kk * 32 + lg * 8;
            #pragma unroll
            for (int nf = 0; nf < 2; ++nf) {
                const int off = (nf * 16 + lr) * 136 + ko;
                const bf16x8 kbh = *(const bf16x8*)&sK[e][0][off];
                const bf16x8 kbl = *(const bf16x8*)&sK[e][1][off];
                s[nf] = mfma16(qfh[kk], kbh, s[nf]);
                s[nf] = mfma16(qfh[kk], kbl, s[nf]);
                s[nf] = mfma16(qfl[kk], kbh, s[nf]);
            }
        }

        // ---- causal mask + online softmax + P split into LDS ----
        const int key0 = kt * 32 + lr;
        #pragma unroll
        for (int i = 0; i < 4; ++i) {
            const int qrow = qr0 + lg * 4 + i;
            float s0 = s[0][i], s1 = s[1][i];
            if (key0 > qrow)      s0 = -1e30f;
            if (key0 + 16 > qrow) s1 = -1e30f;
            float r = fmaxf(s0, s1);
            r = fmaxf(r, __shfl_xor(r, 1));
            r = fmaxf(r, __shfl_xor(r, 2));
            r = fmaxf(r, __shfl_xor(r, 4));
            r = fmaxf(r, __shfl_xor(r, 8));
            const float mnew = fmaxf(mrun[i], r);
            const float corr = expf(mrun[i] - mnew);
            const float p0 = expf(s0 - mnew);
            const float p1 = expf(s1 - mnew);
            float rs = p0 + p1;
            rs += __shfl_xor(rs, 1); rs += __shfl_xor(rs, 2);
            rs += __shfl_xor(rs, 4); rs += __shfl_xor(rs, 8);
            lrun[i] = lrun[i] * corr + rs;
            mrun[i] = mnew;
            const int prow = (lg * 4 + i) * 40;
            const unsigned short h0 = f2bf(p0);
            sP[w][0][prow + lr]      = h0;
            sP[w][1][prow + lr]      = f2bf(p0 - bf2f(h0));
            const unsigned short h1 = f2bf(p1);
            sP[w][0][prow + 16 + lr] = h1;
            sP[w][1][prow + 16 + lr] = f2bf(p1 - bf2f(h1));
            #pragma unroll
            for (int nf = 0; nf < 16; ++nf) o[nf][i] *= corr;
        }

        // ---- PV: O += P * V (split, 3-product); V B-frags from vT staging ----
        const int poff = lr * 40 + lg * 8;
        const bf16x8 ph  = *(const bf16x8*)&sP[w][0][poff];
        const bf16x8 pl_ = *(const bf16x8*)&sP[w][1][poff];
        #pragma unroll
        for (int nf = 0; nf < 16; ++nf) {
            const int voff = (nf * 16 + lr) * 40 + lg * 8;
            const bf16x8 vbh = *(const bf16x8*)&sV[0][voff];
            const bf16x8 vbl = *(const bf16x8*)&sV[1][voff];
            o[nf] = mfma16(ph,  vbh, o[nf]);
            o[nf] = mfma16(ph,  vbl, o[nf]);
            o[nf] = mfma16(pl_, vbh, o[nf]);
        }
        __syncthreads();
    }

    // ---- epilogue: normalize, write att[e][s][h][c] fp32 ----
    float* dst = e ? att2 : att1;
    #pragma unroll
    for (int i = 0; i < 4; ++i) {
        const float inv = 1.0f / lrun[i];
        const int srow = qr0 + lg * 4 + i;
        float* p = dst + ((size_t)srow * 16 + h) * 256 + lr;
        #pragma unroll
        for (int nf = 0; nf < 16; ++nf) p[nf * 16] = o[nf][i] * inv;
    }
}

// ============================================================================
// Combine: attn = attn1 - lambda_full*attn2; RMSNorm over 256; *(1-l_init).
// One wave per (s,h) row; 4 rows per 256-thread block.
// ============================================================================
__global__ __launch_bounds__(256, 4) void combine_kernel(
    const float* __restrict__ att1, const float* __restrict__ att2,
    const float* __restrict__ lq1, const float* __restrict__ lk1,
    const float* __restrict__ lq2, const float* __restrict__ lk2,
    const float* __restrict__ slnw, float* __restrict__ attn_f)
{
    const int t = threadIdx.x, w = t >> 6, ln = t & 63;
    const int idx = blockIdx.x * 4 + w;     // s*16 + h

    float d1 = lq1[ln] * lk1[ln] + lq1[ln + 64] * lk1[ln + 64];
    float d2 = lq2[ln] * lk2[ln] + lq2[ln + 64] * lk2[ln + 64];
    #pragma unroll
    for (int off = 1; off < 64; off <<= 1) {
        d1 += __shfl_xor(d1, off);
        d2 += __shfl_xor(d2, off);
    }
    const float lamf = expf(d1) - expf(d2) + LAMBDA_INIT_F;

    const size_t base = (size_t)idx * 256 + ln * 4;
    const float4 x1 = *(const float4*)(att1 + base);
    const float4 x2 = *(const float4*)(att2 + base);
    float x[4] = { x1.x - lamf * x2.x, x1.y - lamf * x2.y,
                   x1.z - lamf * x2.z, x1.w - lamf * x2.w };
    float ss = x[0] * x[0] + x[1] * x[1] + x[2] * x[2] + x[3] * x[3];
    #pragma unroll
    for (int off = 1; off < 64; off <<= 1) ss += __shfl_xor(ss, off);
    const float sc = ONE_MINUS_LI_F / sqrtf(ss * (1.0f / 256.0f) + 1e-5f);
    const float4 wv = *(const float4*)(slnw + ln * 4);
    float4 y;
    y.x = x[0] * sc * wv.x; y.y = x[1] * sc * wv.y;
    y.z = x[2] * sc * wv.z; y.w = x[3] * sc * wv.w;
    *(float4*)(attn_f + base) = y;      // attn_f[s][h*256+c] == [s][4096]
}

// ============================================================================
extern "C" void kernel_launch(void* const* d_in, const int* in_sizes, int n_in,
                              void* d_out, int out_size, void* d_ws, size_t ws_size,
                              hipStream_t stream)
{
    const float* hs   = (const float*)d_in[0];
    const float* wqkv = (const float*)d_in[1];
    const float* bqkv = (const float*)d_in[2];
    const float* wout = (const float*)d_in[3];
    const float* bout = (const float*)d_in[4];
    const float* lq1  = (const float*)d_in[5];
    const float* lk1  = (const float*)d_in[6];
    const float* lq2  = (const float*)d_in[7];
    const float* lk2  = (const float*)d_in[8];
    const float* slnw = (const float*)d_in[9];

    uint8_t* ws = (uint8_t*)d_ws;
    const size_t NQ = (size_t)16 * 2 * 2048 * 128;      // 8,388,608 elems
    unsigned short* qh_ = (unsigned short*)(ws);
    unsigned short* ql_ = (unsigned short*)(ws + NQ * 2);
    unsigned short* kh_ = (unsigned short*)(ws + NQ * 4);
    unsigned short* kl_ = (unsigned short*)(ws + NQ * 6);
    unsigned short* vh_ = (unsigned short*)(ws + NQ * 8);
    unsigned short* vl_ = (unsigned short*)(ws + NQ * 10);
    float* att2  = (float*)(ws + NQ * 12);              // 33.5 MB
    float* attnf = (float*)(ws + NQ * 12 + NQ * 4);     // 33.5 MB (total 160 MB)
    float* att1  = (float*)d_out;                       // reuse d_out as scratch

    // 1) QKV projection (scatter q/k/vT as split-bf16)
    gemm_split_kernel<0><<<1536, 256, 0, stream>>>(hs, wqkv, bqkv, 2048, 12288, 4096,
        qh_, ql_, kh_, kl_, vh_, vl_, nullptr);
    // 2) dual causal flash attention
    attn_kernel<<<dim3(32, 16), 512, 0, stream>>>(qh_, ql_, kh_, kl_, vh_, vl_, att1, att2);
    // 3) diff + RMSNorm
    combine_kernel<<<8192, 256, 0, stream>>>(att1, att2, lq1, lk1, lq2, lk2, slnw, attnf);
    // 4) output projection
    gemm_split_kernel<1><<<512, 256, 0, stream>>>(attnf, wout, bout, 2048, 4096, 4096,
        nullptr, nullptr, nullptr, nullptr, nullptr, nullptr, (float*)d_out);
}

// Round 3
// 1986.715 us; speedup vs baseline: 1.1161x; 1.1161x over previous
//
#include <hip/hip_runtime.h>
#include <stdint.h>

// ---- problem constants ----
// B=1, S=2048, HID=4096, NH=32, D=128, HP=16
#define LAMBDA_INIT_F 0.35550906759096927f
#define ONE_MINUS_LI_F 0.6444909324090307f
#define QSCALE_F 0.08838834764831845f   // 1/sqrt(128)

typedef __attribute__((ext_vector_type(8))) short bf16x8;
typedef __attribute__((ext_vector_type(4))) float f32x4;

static __device__ __forceinline__ unsigned short f2bf(float x) {
    union { float f; uint32_t u; } v; v.f = x;
    uint32_t r = v.u + 0x7fffu + ((v.u >> 16) & 1u);
    return (unsigned short)(r >> 16);
}
static __device__ __forceinline__ float bf2f(unsigned short h) {
    union { uint32_t u; float f; } v; v.u = ((uint32_t)h) << 16;
    return v.f;
}
static __device__ __forceinline__ f32x4 mfma16(bf16x8 a, bf16x8 b, f32x4 c) {
    return __builtin_amdgcn_mfma_f32_16x16x32_bf16(a, b, c, 0, 0, 0);
}
static __device__ __forceinline__ void split_store8(float4 a, float4 b,
                                                    unsigned short* dh, unsigned short* dl) {
    union { unsigned short u[8]; bf16x8 v; } H, L;
    float f[8] = {a.x, a.y, a.z, a.w, b.x, b.y, b.z, b.w};
    #pragma unroll
    for (int e = 0; e < 8; ++e) {
        unsigned short hh = f2bf(f[e]);
        H.u[e] = hh;
        L.u[e] = f2bf(f[e] - bf2f(hh));
    }
    *(bf16x8*)dh = H.v;
    *(bf16x8*)dl = L.v;
}
static __device__ __forceinline__ void gload_lds16(const unsigned short* g, unsigned short* l) {
    __builtin_amdgcn_global_load_lds(
        (const __attribute__((address_space(1))) void*)g,
        (__attribute__((address_space(3))) void*)l, 16, 0, 0);
}

// ============================================================================
// Streaming fp32 -> (hi,lo) bf16 plane split. 8 elems/thread, fully coalesced.
// ============================================================================
__global__ __launch_bounds__(256) void split_fp32_kernel(
    const float* __restrict__ src,
    unsigned short* __restrict__ hi, unsigned short* __restrict__ lo, int n8)
{
    const int i = blockIdx.x * 256 + threadIdx.x;
    if (i >= n8) return;
    const float4 a = ((const float4*)src)[2 * i];
    const float4 b = ((const float4*)src)[2 * i + 1];
    split_store8(a, b, hi + (size_t)i * 8, lo + (size_t)i * 8);
}

// ============================================================================
// Split-plane bf16 GEMM: C[M,N_c] = (Ah+Al)*(Bh+Bl)^T (3-product) + bias.
// 128x128 tile, BK=32 real-k, 256 threads (4 waves), global_load_lds w=16,
// source-address XOR swizzle (slot ^= row&7) -> 2-way (free) LDS conflicts.
// n0 = global column offset of this B chunk (bias/scatter use n0 + local n).
// MODE 0: QKV epilogue scatter; MODE 1: fp32 C (row stride N_full).
// ============================================================================
template<int MODE>
__global__ __launch_bounds__(256, 3) void gemm_bs_kernel(
    const unsigned short* __restrict__ Ah, const unsigned short* __restrict__ Al,
    const unsigned short* __restrict__ Bh, const unsigned short* __restrict__ Bl,
    const float* __restrict__ bias, int M, int Nc, int K, int n0, int Nfull,
    unsigned short* __restrict__ qh, unsigned short* __restrict__ ql,
    unsigned short* __restrict__ kh, unsigned short* __restrict__ kl,
    unsigned short* __restrict__ vh, unsigned short* __restrict__ vl,
    float* __restrict__ Cout)
{
    // [row(128)][slot(8)][8 bf16]; phys slot p holds logical slot p^(row&7).
    // logical slot: 0..3 = hi plane k-chunk, 4..7 = lo plane k-chunk. 16KB each.
    __shared__ __attribute__((aligned(16))) unsigned short sA[128 * 64];
    __shared__ __attribute__((aligned(16))) unsigned short sB[128 * 64];

    const int nwg = gridDim.x;
    const int bid = blockIdx.x;
    const int wg  = (bid & 7) * (nwg >> 3) + (bid >> 3);   // XCD swizzle (nwg%8==0)
    const int mt  = M >> 7;
    const int bm  = wg % mt, bn = wg / mt;
    const int rowA = bm << 7, rowB = bn << 7;

    const int t = threadIdx.x, ln = t & 63, w = t >> 6;
    const int wm = (w >> 1) << 6, wn = (w & 1) << 6;
    const int lr = ln & 15, lg = ln >> 4;

    // ---- staging source pointers (pre-swizzled per-lane global addresses) ----
    const int r8 = ln >> 3, p = ln & 7;
    const int sl = p ^ r8;                 // logical slot this lane fetches
    const unsigned short* pA = (sl < 4) ? Ah : Al;
    const unsigned short* pB = (sl < 4) ? Bh : Bl;
    const int co = (sl & 3) << 3;          // k-chunk offset in elems
    const unsigned short* baseA[4];
    const unsigned short* baseB[4];
    unsigned short* ldsA[4];
    unsigned short* ldsB[4];
    #pragma unroll
    for (int i = 0; i < 4; ++i) {
        const int r = (w << 5) + i * 8;    // wave w stages rows w*32..w*32+31
        baseA[i] = pA + (size_t)(rowA + r + r8) * K + co;
        baseB[i] = pB + (size_t)(rowB + r + r8) * K + co;
        ldsA[i]  = &sA[r << 6];
        ldsB[i]  = &sB[r << 6];
    }

    const f32x4 zero4 = {0.f, 0.f, 0.f, 0.f};
    f32x4 acc[4][4];
    #pragma unroll
    for (int a = 0; a < 4; ++a)
        #pragma unroll
        for (int b = 0; b < 4; ++b) acc[a][b] = zero4;

    for (int k0 = 0; k0 < K; k0 += 32) {
        #pragma unroll
        for (int i = 0; i < 4; ++i) {
            gload_lds16(baseA[i] + k0, ldsA[i]);
            gload_lds16(baseB[i] + k0, ldsB[i]);
        }
        __syncthreads();                   // compiler drains vmcnt before barrier

        const int so = (lg ^ (lr & 7)) << 3;   // hi-plane physical slot offset
        bf16x8 ah[4], al_[4];
        #pragma unroll
        for (int mf = 0; mf < 4; ++mf) {
            const int ar = (wm + mf * 16 + lr) << 6;
            ah[mf]  = *(const bf16x8*)&sA[ar + so];
            al_[mf] = *(const bf16x8*)&sA[ar + (so ^ 32)];
        }
        #pragma unroll
        for (int nf = 0; nf < 4; ++nf) {
            const int br = (wn + nf * 16 + lr) << 6;
            const bf16x8 bh  = *(const bf16x8*)&sB[br + so];
            const bf16x8 bl_ = *(const bf16x8*)&sB[br + (so ^ 32)];
            #pragma unroll
            for (int mf = 0; mf < 4; ++mf) {
                acc[mf][nf] = mfma16(ah[mf],  bh,  acc[mf][nf]);
                acc[mf][nf] = mfma16(ah[mf],  bl_, acc[mf][nf]);
                acc[mf][nf] = mfma16(al_[mf], bh,  acc[mf][nf]);
            }
        }
        __syncthreads();
    }

    // ---- epilogue (C/D layout: col = lane&15, row = (lane>>4)*4 + i) ----
    #pragma unroll
    for (int nf = 0; nf < 4; ++nf) {
        const int n  = n0 + (bn << 7) + wn + nf * 16 + lr;   // global column
        const float bv = bias[n];
        #pragma unroll
        for (int mf = 0; mf < 4; ++mf) {
            #pragma unroll
            for (int i = 0; i < 4; ++i) {
                const int srow = (bm << 7) + wm + mf * 16 + lg * 4 + i;
                const float val = acc[mf][nf][i] + bv;
                if (MODE == 0) {
                    if (n < 4096) {           // q: pre-scale by 1/sqrt(D)
                        const int hh = n >> 8, e2 = (n >> 7) & 1, d = n & 127;
                        const float qv = val * QSCALE_F;
                        const unsigned short hi = f2bf(qv);
                        const unsigned short lo = f2bf(qv - bf2f(hi));
                        const size_t o = ((size_t)((hh * 2 + e2) * 2048 + srow)) * 128 + d;
                        qh[o] = hi; ql[o] = lo;
                    } else if (n < 8192) {    // k
                        const int n2 = n - 4096;
                        const int hh = n2 >> 8, e2 = (n2 >> 7) & 1, d = n2 & 127;
                        const unsigned short hi = f2bf(val);
                        const unsigned short lo = f2bf(val - bf2f(hi));
                        const size_t o = ((size_t)((hh * 2 + e2) * 2048 + srow)) * 128 + d;
                        kh[o] = hi; kl[o] = lo;
                    } else {                  // v: store transposed vT[h][c][s]
                        const int n2 = n - 8192;
                        const int hh = n2 >> 8, cc = n2 & 255;
                        const unsigned short hi = f2bf(val);
                        const unsigned short lo = f2bf(val - bf2f(hi));
                        const size_t o = ((size_t)(hh * 256 + cc)) * 2048 + srow;
                        vh[o] = hi; vl[o] = lo;
                    }
                } else {
                    Cout[(size_t)srow * Nfull + n] = val;
                }
            }
        }
    }
}

// ============================================================================
// OLD reg-staging split GEMM (fallback only; unreachable given known ws_size).
// ============================================================================
template<int MODE>
__global__ __launch_bounds__(256, 2) void gemm_split_kernel(
    const float* __restrict__ A, const float* __restrict__ Bm,
    const float* __restrict__ bias, int M, int N, int K,
    unsigned short* __restrict__ qh, unsigned short* __restrict__ ql,
    unsigned short* __restrict__ kh, unsigned short* __restrict__ kl,
    unsigned short* __restrict__ vh, unsigned short* __restrict__ vl,
    float* __restrict__ Cout)
{
    __shared__ unsigned short sAh[128 * 72], sAl[128 * 72];
    __shared__ unsigned short sBh[128 * 72], sBl[128 * 72];

    const int nwg = gridDim.x;
    const int bid = blockIdx.x;
    const int wg  = (bid & 7) * (nwg >> 3) + (bid >> 3);
    const int mt  = M >> 7;
    const int bm  = wg % mt, bn = wg / mt;
    const int rowA = bm << 7, rowB = bn << 7;

    const int t  = threadIdx.x;
    const int g  = t & 7, mr = t >> 3;
    const int ln = t & 63, w = t >> 6;
    const int wm = (w >> 1) << 6, wn = (w & 1) << 6;
    const int lr = ln & 15, lg = ln >> 4;

    const f32x4 zero4 = {0.f, 0.f, 0.f, 0.f};
    f32x4 acc[4][4];
    #pragma unroll
    for (int a = 0; a < 4; ++a)
        #pragma unroll
        for (int b = 0; b < 4; ++b) acc[a][b] = zero4;

    for (int k0 = 0; k0 < K; k0 += 64) {
        float4 st[16];
        #pragma unroll
        for (int i = 0; i < 4; ++i) {
            const float* sa = A  + (size_t)(rowA + mr + 32 * i) * K + k0 + g * 8;
            const float* sb = Bm + (size_t)(rowB + mr + 32 * i) * K + k0 + g * 8;
            st[2 * i]     = *(const float4*)sa;
            st[2 * i + 1] = *(const float4*)(sa + 4);
            st[8 + 2 * i]     = *(const float4*)sb;
            st[8 + 2 * i + 1] = *(const float4*)(sb + 4);
        }
        #pragma unroll
        for (int i = 0; i < 4; ++i) {
            const int off = (mr + 32 * i) * 72 + g * 8;
            split_store8(st[2 * i],     st[2 * i + 1],     &sAh[off], &sAl[off]);
            split_store8(st[8 + 2 * i], st[8 + 2 * i + 1], &sBh[off], &sBl[off]);
        }
        __syncthreads();

        #pragma unroll
        for (int kk = 0; kk < 2; ++kk) {
            bf16x8 ah[4], al_[4], bh[4], bl_[4];
            const int ko = kk * 32 + lg * 8;
            #pragma unroll
            for (int mf = 0; mf < 4; ++mf) {
                const int off = (wm + mf * 16 + lr) * 72 + ko;
                ah[mf]  = *(const bf16x8*)&sAh[off];
                al_[mf] = *(const bf16x8*)&sAl[off];
            }
            #pragma unroll
            for (int nf = 0; nf < 4; ++nf) {
                const int off = (wn + nf * 16 + lr) * 72 + ko;
                bh[nf]  = *(const bf16x8*)&sBh[off];
                bl_[nf] = *(const bf16x8*)&sBl[off];
            }
            #pragma unroll
            for (int mf = 0; mf < 4; ++mf)
                #pragma unroll
                for (int nf = 0; nf < 4; ++nf) {
                    acc[mf][nf] = mfma16(ah[mf],  bh[nf],  acc[mf][nf]);
                    acc[mf][nf] = mfma16(ah[mf],  bl_[nf], acc[mf][nf]);
                    acc[mf][nf] = mfma16(al_[mf], bh[nf],  acc[mf][nf]);
                }
        }
        __syncthreads();
    }

    #pragma unroll
    for (int nf = 0; nf < 4; ++nf) {
        const int n  = (bn << 7) + wn + nf * 16 + lr;
        const float bv = bias[n];
        #pragma unroll
        for (int mf = 0; mf < 4; ++mf) {
            #pragma unroll
            for (int i = 0; i < 4; ++i) {
                const int srow = (bm << 7) + wm + mf * 16 + lg * 4 + i;
                const float val = acc[mf][nf][i] + bv;
                if (MODE == 0) {
                    if (n < 4096) {
                        const int hh = n >> 8, e2 = (n >> 7) & 1, d = n & 127;
                        const float qv = val * QSCALE_F;
                        const unsigned short hi = f2bf(qv);
                        const unsigned short lo = f2bf(qv - bf2f(hi));
                        const size_t o = ((size_t)((hh * 2 + e2) * 2048 + srow)) * 128 + d;
                        qh[o] = hi; ql[o] = lo;
                    } else if (n < 8192) {
                        const int n2 = n - 4096;
                        const int hh = n2 >> 8, e2 = (n2 >> 7) & 1, d = n2 & 127;
                        const unsigned short hi = f2bf(val);
                        const unsigned short lo = f2bf(val - bf2f(hi));
                        const size_t o = ((size_t)((hh * 2 + e2) * 2048 + srow)) * 128 + d;
                        kh[o] = hi; kl[o] = lo;
                    } else {
                        const int n2 = n - 8192;
                        const int hh = n2 >> 8, cc = n2 & 255;
                        const unsigned short hi = f2bf(val);
                        const unsigned short lo = f2bf(val - bf2f(hi));
                        const size_t o = ((size_t)(hh * 256 + cc)) * 2048 + srow;
                        vh[o] = hi; vl[o] = lo;
                    }
                } else {
                    Cout[(size_t)srow * N + n] = val;
                }
            }
        }
    }
}

// ============================================================================
// Flash attention, dual-e per block (shared V staging). Unchanged (verified R1).
// ============================================================================
__global__ __launch_bounds__(512, 2) void attn_kernel(
    const unsigned short* __restrict__ qh, const unsigned short* __restrict__ ql,
    const unsigned short* __restrict__ kh, const unsigned short* __restrict__ kl,
    const unsigned short* __restrict__ vh, const unsigned short* __restrict__ vl,
    float* __restrict__ att1, float* __restrict__ att2)
{
    __shared__ unsigned short sK[2][2][32 * 136];
    __shared__ unsigned short sV[2][256 * 40];
    __shared__ unsigned short sP[8][2][16 * 40];

    const int qt = blockIdx.x;
    const int h  = blockIdx.y;
    const int t  = threadIdx.x;
    const int w  = t >> 6, ln = t & 63;
    const int e  = w >> 2, wq = w & 3;
    const int lr = ln & 15, lg = ln >> 4;
    const int qr0 = qt * 64 + wq * 16;

    bf16x8 qfh[4], qfl[4];
    {
        const size_t qoff = ((size_t)((h * 2 + e) * 2048 + qr0 + lr)) * 128 + lg * 8;
        #pragma unroll
        for (int kk = 0; kk < 4; ++kk) {
            qfh[kk] = *(const bf16x8*)(qh + qoff + kk * 32);
            qfl[kk] = *(const bf16x8*)(ql + qoff + kk * 32);
        }
    }

    const f32x4 zero4 = {0.f, 0.f, 0.f, 0.f};
    f32x4 o[16];
    #pragma unroll
    for (int nf = 0; nf < 16; ++nf) o[nf] = zero4;
    float mrun[4] = {-3.0e38f, -3.0e38f, -3.0e38f, -3.0e38f};
    float lrun[4] = {0.f, 0.f, 0.f, 0.f};

    const int ktiles = qt * 2 + 2;
    for (int kt = 0; kt < ktiles; ++kt) {
        bf16x8 stg[8];
        unsigned short* dstp[8];
        #pragma unroll
        for (int i = 0; i < 8; ++i) {
            const int gid = i * 512 + t;
            if (gid < 2048) {
                const int buf = gid >> 9, r = gid & 511;
                const int e2 = buf >> 1, hl = buf & 1;
                const int key = r >> 4, dg = r & 15;
                const unsigned short* base = hl ? kl : kh;
                stg[i]  = *(const bf16x8*)(base +
                          ((size_t)((h * 2 + e2) * 2048 + kt * 32 + key)) * 128 + dg * 8);
                dstp[i] = &sK[e2][hl][key * 136 + dg * 8];
            } else {
                const int r2 = gid - 2048;
                const int hl = r2 >> 10, r = r2 & 1023;
                const int c = r >> 2, kg = r & 3;
                const unsigned short* base = hl ? vl : vh;
                stg[i]  = *(const bf16x8*)(base +
                          ((size_t)(h * 256 + c)) * 2048 + kt * 32 + kg * 8);
                dstp[i] = &sV[hl][c * 40 + kg * 8];
            }
        }
        #pragma unroll
        for (int i = 0; i < 8; ++i) *(bf16x8*)dstp[i] = stg[i];
        __syncthreads();

        f32x4 s[2];
        s[0] = zero4; s[1] = zero4;
        #pragma unroll
        for (int kk = 0; kk < 4; ++kk) {
            const int ko = kk * 32 + lg * 8;
            #pragma unroll
            for (int nf = 0; nf < 2; ++nf) {
                const int off = (nf * 16 + lr) * 136 + ko;
                const bf16x8 kbh = *(const bf16x8*)&sK[e][0][off];
                const bf16x8 kbl = *(const bf16x8*)&sK[e][1][off];
                s[nf] = mfma16(qfh[kk], kbh, s[nf]);
                s[nf] = mfma16(qfh[kk], kbl, s[nf]);
                s[nf] = mfma16(qfl[kk], kbh, s[nf]);
            }
        }

        const int key0 = kt * 32 + lr;
        #pragma unroll
        for (int i = 0; i < 4; ++i) {
            const int qrow = qr0 + lg * 4 + i;
            float s0 = s[0][i], s1 = s[1][i];
            if (key0 > qrow)      s0 = -1e30f;
            if (key0 + 16 > qrow) s1 = -1e30f;
            float r = fmaxf(s0, s1);
            r = fmaxf(r, __shfl_xor(r, 1));
            r = fmaxf(r, __shfl_xor(r, 2));
            r = fmaxf(r, __shfl_xor(r, 4));
            r = fmaxf(r, __shfl_xor(r, 8));
            const float mnew = fmaxf(mrun[i], r);
            const float corr = expf(mrun[i] - mnew);
            const float p0 = expf(s0 - mnew);
            const float p1 = expf(s1 - mnew);
            float rs = p0 + p1;
            rs += __shfl_xor(rs, 1); rs += __shfl_xor(rs, 2);
            rs += __shfl_xor(rs, 4); rs += __shfl_xor(rs, 8);
            lrun[i] = lrun[i] * corr + rs;
            mrun[i] = mnew;
            const int prow = (lg * 4 + i) * 40;
            const unsigned short h0 = f2bf(p0);
            sP[w][0][prow + lr]      = h0;
            sP[w][1][prow + lr]      = f2bf(p0 - bf2f(h0));
            const unsigned short h1 = f2bf(p1);
            sP[w][0][prow + 16 + lr] = h1;
            sP[w][1][prow + 16 + lr] = f2bf(p1 - bf2f(h1));
            #pragma unroll
            for (int nf = 0; nf < 16; ++nf) o[nf][i] *= corr;
        }

        const int poff = lr * 40 + lg * 8;
        const bf16x8 ph  = *(const bf16x8*)&sP[w][0][poff];
        const bf16x8 pl_ = *(const bf16x8*)&sP[w][1][poff];
        #pragma unroll
        for (int nf = 0; nf < 16; ++nf) {
            const int voff = (nf * 16 + lr) * 40 + lg * 8;
            const bf16x8 vbh = *(const bf16x8*)&sV[0][voff];
            const bf16x8 vbl = *(const bf16x8*)&sV[1][voff];
            o[nf] = mfma16(ph,  vbh, o[nf]);
            o[nf] = mfma16(ph,  vbl, o[nf]);
            o[nf] = mfma16(pl_, vbh, o[nf]);
        }
        __syncthreads();
    }

    float* dst = e ? att2 : att1;
    #pragma unroll
    for (int i = 0; i < 4; ++i) {
        const float inv = 1.0f / lrun[i];
        const int srow = qr0 + lg * 4 + i;
        float* p = dst + ((size_t)srow * 16 + h) * 256 + lr;
        #pragma unroll
        for (int nf = 0; nf < 16; ++nf) p[nf * 16] = o[nf][i] * inv;
    }
}

// ============================================================================
// Combine: diff + RMSNorm. SPLITOUT=1 writes bf16 hi/lo planes for out-proj.
// ============================================================================
template<int SPLITOUT>
__global__ __launch_bounds__(256, 4) void combine_kernel(
    const float* __restrict__ att1, const float* __restrict__ att2,
    const float* __restrict__ lq1, const float* __restrict__ lk1,
    const float* __restrict__ lq2, const float* __restrict__ lk2,
    const float* __restrict__ slnw, float* __restrict__ attn_f,
    unsigned short* __restrict__ aoh, unsigned short* __restrict__ aol)
{
    const int t = threadIdx.x, w = t >> 6, ln = t & 63;
    const int idx = blockIdx.x * 4 + w;

    float d1 = lq1[ln] * lk1[ln] + lq1[ln + 64] * lk1[ln + 64];
    float d2 = lq2[ln] * lk2[ln] + lq2[ln + 64] * lk2[ln + 64];
    #pragma unroll
    for (int off = 1; off < 64; off <<= 1) {
        d1 += __shfl_xor(d1, off);
        d2 += __shfl_xor(d2, off);
    }
    const float lamf = expf(d1) - expf(d2) + LAMBDA_INIT_F;

    const size_t base = (size_t)idx * 256 + ln * 4;
    const float4 x1 = *(const float4*)(att1 + base);
    const float4 x2 = *(const float4*)(att2 + base);
    float x[4] = { x1.x - lamf * x2.x, x1.y - lamf * x2.y,
                   x1.z - lamf * x2.z, x1.w - lamf * x2.w };
    float ss = x[0] * x[0] + x[1] * x[1] + x[2] * x[2] + x[3] * x[3];
    #pragma unroll
    for (int off = 1; off < 64; off <<= 1) ss += __shfl_xor(ss, off);
    const float sc = ONE_MINUS_LI_F / sqrtf(ss * (1.0f / 256.0f) + 1e-5f);
    const float4 wv = *(const float4*)(slnw + ln * 4);
    float y[4] = { x[0] * sc * wv.x, x[1] * sc * wv.y,
                   x[2] * sc * wv.z, x[3] * sc * wv.w };
    if (SPLITOUT) {
        union { unsigned short u[4]; uint64_t q; } H, L;
        #pragma unroll
        for (int j = 0; j < 4; ++j) {
            H.u[j] = f2bf(y[j]);
            L.u[j] = f2bf(y[j] - bf2f(H.u[j]));
        }
        *(uint64_t*)(aoh + base) = H.q;
        *(uint64_t*)(aol + base) = L.q;
    } else {
        float4 yv = { y[0], y[1], y[2], y[3] };
        *(float4*)(attn_f + base) = yv;
    }
}

// ============================================================================
// Orchestration. Fast path fits in 167,772,160 B (== R0's proven ws usage):
//   [0,100.7MB)      q/k/v hi/lo planes  -> later Aoh/Aol + out-proj W planes
//   [100.7,134.2MB)  Hs planes (gemm phase) == att2 (attn phase onward)
//   [134.2,167.8MB)  Wqkv chunk planes (6 chunks of 2048 cols, serialized)
// ============================================================================
extern "C" void kernel_launch(void* const* d_in, const int* in_sizes, int n_in,
                              void* d_out, int out_size, void* d_ws, size_t ws_size,
                              hipStream_t stream)
{
    const float* hs   = (const float*)d_in[0];
    const float* wqkv = (const float*)d_in[1];
    const float* bqkv = (const float*)d_in[2];
    const float* wout = (const float*)d_in[3];
    const float* bout = (const float*)d_in[4];
    const float* lq1  = (const float*)d_in[5];
    const float* lk1  = (const float*)d_in[6];
    const float* lq2  = (const float*)d_in[7];
    const float* lk2  = (const float*)d_in[8];
    const float* slnw = (const float*)d_in[9];

    uint8_t* ws = (uint8_t*)d_ws;
    const size_t NQ = (size_t)16 * 2 * 2048 * 128;      // 8,388,608 elems
    const size_t PL = NQ * 2;                           // 16,777,216 B per plane
    unsigned short* qh_ = (unsigned short*)(ws);
    unsigned short* ql_ = (unsigned short*)(ws + PL);
    unsigned short* kh_ = (unsigned short*)(ws + 2 * PL);
    unsigned short* kl_ = (unsigned short*)(ws + 3 * PL);
    unsigned short* vh_ = (unsigned short*)(ws + 4 * PL);
    unsigned short* vl_ = (unsigned short*)(ws + 5 * PL);
    float* att1 = (float*)d_out;
    float* att2 = (float*)(ws + 6 * PL);                // [100.7,134.2MB)

    const size_t NEED = 167772160ull;
    if (ws_size >= NEED) {
        unsigned short* Hsh = (unsigned short*)(ws + 6 * PL);           // == att2 region
        unsigned short* Hsl = (unsigned short*)(ws + 7 * PL);
        unsigned short* Wbh = (unsigned short*)(ws + 8 * PL);           // chunk planes
        unsigned short* Wbl = (unsigned short*)(ws + 9 * PL);
        unsigned short* Aoh = (unsigned short*)(ws);                    // reuse q planes
        unsigned short* Aol = (unsigned short*)(ws + PL);
        unsigned short* Oh  = (unsigned short*)(ws + 2 * PL);           // reuse k planes
        unsigned short* Ol  = (unsigned short*)(ws + 4 * PL);           // reuse v planes

        // 1) split hidden states (33.5 MB planes)
        split_fp32_kernel<<<4096, 256, 0, stream>>>(hs, Hsh, Hsl, 1048576);
        // 2) QKV projection in 6 chunks of 2048 cols (split chunk -> gemm)
        for (int c = 0; c < 6; ++c) {
            split_fp32_kernel<<<4096, 256, 0, stream>>>(
                wqkv + (size_t)c * 2048 * 4096, Wbh, Wbl, 1048576);
            gemm_bs_kernel<0><<<256, 256, 0, stream>>>(Hsh, Hsl, Wbh, Wbl, bqkv,
                2048, 2048, 4096, c * 2048, 12288,
                qh_, ql_, kh_, kl_, vh_, vl_, nullptr);
        }
        // 3) dual causal flash attention (att2 overwrites dead Hs planes)
        attn_kernel<<<dim3(32, 16), 512, 0, stream>>>(qh_, ql_, kh_, kl_, vh_, vl_,
                                                      att1, att2);
        // 4) diff + RMSNorm -> split planes (reuse dead q-plane region)
        combine_kernel<1><<<8192, 256, 0, stream>>>(att1, att2, lq1, lk1, lq2, lk2, slnw,
            nullptr, Aoh, Aol);
        // 5) split out_w (67.1 MB planes into dead k/v-plane region)
        split_fp32_kernel<<<8192, 256, 0, stream>>>(wout, Oh, Ol, 2097152);
        // 6) output projection
        gemm_bs_kernel<1><<<512, 256, 0, stream>>>(Aoh, Aol, Oh, Ol, bout,
            2048, 4096, 4096, 0, 4096,
            nullptr, nullptr, nullptr, nullptr, nullptr, nullptr, (float*)d_out);
    } else {
        // ---- fallback: R0 path (reg-staging in-GEMM split) ----
        float* attnf = (float*)(ws + 6 * PL + NQ * 4);
        gemm_split_kernel<0><<<1536, 256, 0, stream>>>(hs, wqkv, bqkv, 2048, 12288, 4096,
            qh_, ql_, kh_, kl_, vh_, vl_, nullptr);
        attn_kernel<<<dim3(32, 16), 512, 0, stream>>>(qh_, ql_, kh_, kl_, vh_, vl_,
                                                      att1, att2);
        combine_kernel<0><<<8192, 256, 0, stream>>>(att1, att2, lq1, lk1, lq2, lk2, slnw,
            attnf, nullptr, nullptr);
        gemm_split_kernel<1><<<512, 256, 0, stream>>>(attnf, wout, bout, 2048, 4096, 4096,
            nullptr, nullptr, nullptr, nullptr, nullptr, nullptr, (float*)d_out);
    }
}